// Round 1
// baseline (105.441 us; speedup 1.0000x reference)
//
#include <hip/hip_runtime.h>
#include <stdint.h>

#define NB 32
#define NA 48
#define HIN 64
#define EIN 32
#define HH 64
#define HG 16
#define NCELLS 5
#define GH 1024        // HG*HH
#define EROW 40        // shorts per staged E row (32 + 8 pad; 80 B, 16B-aligned rows)
#define P3 3           // nodes per block
#define ESTR 1088      // Esum_s floats per node (16 rows x 68 padded)

typedef __attribute__((ext_vector_type(8))) short short8;   // 8 x bf16 (4 VGPRs)
typedef __attribute__((ext_vector_type(4))) float float4v;  // 4 x f32

__device__ __forceinline__ unsigned short f2bf(float f) {
    union { float f; unsigned int u; } v; v.f = f;
    unsigned int u = v.u + 0x7FFF + ((v.u >> 16) & 1);      // RNE
    return (unsigned short)(u >> 16);
}
__device__ __forceinline__ float bf2f(unsigned short s) {
    union { unsigned int u; float f; } v; v.u = ((unsigned int)s) << 16;
    return v.f;
}

// Edge phase for 3 nodes, specialized on block-uniform max tile count NTMAX.
// B-fragments are now built inline from W_e fp32 (identical hi/lo split as the
// old prep kernel, so numerics are bit-identical): 8 stride-4KB dword loads per
// lane per tile = same bytes/transactions as the old bf16-pair loads, plus
// ~48 VALU of convert per tile. This removes the prep kernel + workspace
// round trip entirely.
template <int NTMAX>
__device__ __forceinline__ void edge_phase3(
    const float* __restrict__ W_e, const float* __restrict__ b_e,
    const unsigned short* EcolH, const unsigned short* EcolL,   // [3][48][EROW]
    const float* mask_s,                                        // [3][48]
    int wave, int lane, int mrow, int quad,
    float* Esum_s)                                              // [3][ESTR]
{
    const float4v zero4 = {0.0f, 0.0f, 0.0f, 0.0f};
    short8 aH[P3][NTMAX ? NTMAX : 1], aL[P3][NTMAX ? NTMAX : 1];
    #pragma unroll
    for (int p = 0; p < P3; ++p)
        #pragma unroll
        for (int rt = 0; rt < NTMAX; ++rt) {
            const int off = (p * 48 + 16 * rt + mrow) * EROW + quad * 8;
            aH[p][rt] = *(const short8*)(EcolH + off);
            aL[p][rt] = *(const short8*)(EcolL + off);
        }

    #pragma unroll 4
    for (int t = 0; t < 16; ++t) {
        const int ct = wave * 16 + t;
        // inline split-bf16 B-fragment from W_e (was: hiB/loB workspace loads)
        short8 bfH, bfL;
        #pragma unroll
        for (int jj = 0; jj < 8; ++jj) {
            const float x = W_e[(quad * 8 + jj) * GH + ct * 16 + mrow];
            const unsigned short hb = f2bf(x);
            bfH[jj] = (short)hb;
            bfL[jj] = (short)f2bf(x - bf2f(hb));
        }
        const float be = b_e[ct * 16 + mrow];   // L1-hot, 16-lane broadcast
        float psum[P3] = {0.0f, 0.0f, 0.0f};
        #pragma unroll
        for (int p = 0; p < P3; ++p) {
            #pragma unroll
            for (int rt = 0; rt < NTMAX; ++rt) {
                // split-bf16: A_lo*B_hi + A_hi*B_lo + A_hi*B_hi (fp32 acc)
                float4v d = __builtin_amdgcn_mfma_f32_16x16x32_bf16(aL[p][rt], bfH, zero4, 0, 0, 0);
                d = __builtin_amdgcn_mfma_f32_16x16x32_bf16(aH[p][rt], bfL, d, 0, 0, 0);
                d = __builtin_amdgcn_mfma_f32_16x16x32_bf16(aH[p][rt], bfH, d, 0, 0, 0);
                const float4v mk = *(const float4v*)(mask_s + p * 48 + rt * 16 + quad * 4);
                #pragma unroll
                for (int rg = 0; rg < 4; ++rg)
                    psum[p] = fmaf(fmaxf(d[rg] + be, 0.0f), mk[rg], psum[p]);
            }
        }
        #pragma unroll
        for (int p = 0; p < P3; ++p) {
            float ps = psum[p];
            ps += __shfl_xor(ps, 16);
            ps += __shfl_xor(ps, 32);
            if (lane < 16) {
                const int c = ct * 16 + lane;
                Esum_s[p * ESTR + (c >> 6) * 68 + (c & 63)] = ps;
            }
        }
    }
}

// One block per 3 nodes. Grid 512 = exactly 2 blocks/CU (balanced, one round).
// Single kernel: no prep, no workspace. Gate weights live in 80 VGPRs/thread
// across the 5 GRU iterations (was: 61.4 KB/block/iter streamed from L2).
// GRU barriers 3->2 per iter: update->M is wave-local (update thread (p,c) and
// the node-p M phase are both wave p; same-wave LDS ops are ordered).
__global__ __launch_bounds__(256, 2) void fused_kernel(
    const float* __restrict__ A,  const float* __restrict__ h,
    const float* __restrict__ E,
    const float* __restrict__ W_h, const float* __restrict__ b_h,
    const float* __restrict__ W_e, const float* __restrict__ b_e,
    const float* __restrict__ W_ih, const float* __restrict__ b_ih,
    const float* __restrict__ W_hh, const float* __restrict__ b_hh,
    float* __restrict__ out)
{
    __shared__ unsigned short EcolH[P3 * NA * EROW];  // compacted E rows, bf16 hi
    __shared__ unsigned short EcolL[P3 * NA * EROW];  // bf16 lo (residual)
    __shared__ float Esum_s[P3 * ESTR];
    __shared__ float mask_s[P3 * 48];                 // [p][row] validity
    __shared__ int   ilist[P3 * NA];
    __shared__ int   cnt_s[P3];
    __shared__ float hc_s[P3 * HH];
    __shared__ float M_s[P3 * HG];
    __shared__ float gsum_s[P3 * 2 * HH];
    __shared__ float gin_s[P3 * HH], ghn_s[P3 * HH];

    const int node0 = blockIdx.x * P3;          // 3 nodes share batch b (48%3==0)
    const int b = node0 / NA, j0 = node0 - b * NA;
    const int tid = threadIdx.x, lane = tid & 63, wave = tid >> 6;
    const int mrow = lane & 15, quad = lane >> 4;

    // ---- ballot phase: waves 0..2 build compacted active-row lists ----
    if (wave < P3) {
        const float a = (lane < NA) ? A[((size_t)b * NA + lane) * NA + (j0 + wave)] : 0.0f;
        const unsigned long long m = __ballot(a != 0.0f);
        if (a != 0.0f) ilist[wave * NA + __popcll(m & ((1ull << lane) - 1ull))] = lane;
        if (lane == 0) cnt_s[wave] = (int)__popcll(m);
    }
    __syncthreads();

    // ---- stage compacted E rows -> split bf16 LDS; zero-pad rows >= cnt ----
    for (int idx = tid; idx < P3 * NA * 8; idx += 256) {
        const int p = idx / (NA * 8);
        const int rem = idx - p * (NA * 8);
        const int r = rem >> 3, q = rem & 7;
        uint2 hv2 = make_uint2(0u, 0u), lv2 = make_uint2(0u, 0u);
        if (r < cnt_s[p]) {
            const int i = ilist[p * NA + r];
            const float4 ev = *(const float4*)(E + ((size_t)(b * NA + i) * NA + (j0 + p)) * EIN + 4 * q);
            unsigned short h0 = f2bf(ev.x), h1 = f2bf(ev.y), h2 = f2bf(ev.z), h3 = f2bf(ev.w);
            unsigned short l0 = f2bf(ev.x - bf2f(h0)), l1 = f2bf(ev.y - bf2f(h1));
            unsigned short l2 = f2bf(ev.z - bf2f(h2)), l3 = f2bf(ev.w - bf2f(h3));
            hv2 = make_uint2((unsigned int)h0 | ((unsigned int)h1 << 16),
                             (unsigned int)h2 | ((unsigned int)h3 << 16));
            lv2 = make_uint2((unsigned int)l0 | ((unsigned int)l1 << 16),
                             (unsigned int)l2 | ((unsigned int)l3 << 16));
        }
        *(uint2*)(&EcolH[(p * NA + r) * EROW + 4 * q]) = hv2;
        *(uint2*)(&EcolL[(p * NA + r) * EROW + 4 * q]) = lv2;
    }
    // validity masks for the MFMA epilogue
    if (tid < P3 * 48) {
        const int p = tid / 48, rem = tid - p * 48;
        mask_s[tid] = (rem < cnt_s[p]) ? 1.0f : 0.0f;   // rem = rt*16+ri = global row
    }
    __syncthreads();

    const int nt0 = (cnt_s[0] + 15) >> 4, nt1 = (cnt_s[1] + 15) >> 4, nt2 = (cnt_s[2] + 15) >> 4;
    int ntmax = nt0 > nt1 ? nt0 : nt1; ntmax = ntmax > nt2 ? ntmax : nt2;   // block-uniform

    if (ntmax == 0)
        edge_phase3<0>(W_e, b_e, EcolH, EcolL, mask_s, wave, lane, mrow, quad, Esum_s);
    else if (ntmax == 1)
        edge_phase3<1>(W_e, b_e, EcolH, EcolL, mask_s, wave, lane, mrow, quad, Esum_s);
    else if (ntmax == 2)
        edge_phase3<2>(W_e, b_e, EcolH, EcolL, mask_s, wave, lane, mrow, quad, Esum_s);
    else
        edge_phase3<3>(W_e, b_e, EcolH, EcolL, mask_s, wave, lane, mrow, quad, Esum_s);

    // gate biases (shared across the 3 nodes)
    float bihc = 0.0f, bhhc = 0.0f;
    if (tid < 3 * HH) { bihc = b_ih[tid]; bhhc = b_hh[tid]; }

    // hv_p = relu(h_p @ W_h + b_h) * maskh_p  (wave p handles node p)
    if (wave < P3) {
        const int node = node0 + wave;
        const float a = (lane < NA) ? A[(size_t)node * NA + lane] : 0.0f;
        const unsigned long long mrowm = __ballot(a != 0.0f);
        const float maskh = (mrowm != 0ull) ? 1.0f : 0.0f;
        const float hr = h[(size_t)node * HIN + lane];
        float acc = b_h[lane];
        #pragma unroll
        for (int k = 0; k < HIN; ++k)
            acc = fmaf(__shfl(hr, k), W_h[k * HH + lane], acc);
        hc_s[wave * HH + lane] = fmaxf(acc, 0.0f) * maskh;
    }

    // ---- gate weights -> registers, ONCE (80 VGPRs/thread, reused 5 iters).
    // Loaded here (post-edge-phase, low register pressure); sched_barrier pins
    // the loads so they can't be hoisted across the edge phase.
    __builtin_amdgcn_sched_barrier(0);
    float4 w_r[20];
    if (tid < 192) {
        #pragma unroll
        for (int j = 0; j < 4; ++j)
            w_r[j] = *(const float4*)(W_ih + tid * HG + 4 * j);
        #pragma unroll
        for (int j = 0; j < 16; ++j)
            w_r[4 + j] = *(const float4*)(W_hh + tid * HH + 4 * j);
    }
    __syncthreads();

    // ---- 5 GRUCell iterations for 3 nodes; weights register-resident ----
    #pragma unroll 1
    for (int it = 0; it < NCELLS; ++it) {
        if (tid < 192) {   // M[p][g] = Esum[p][g,:] . hc[p]; 4 threads per (p,g)
            const int p = tid >> 6, s = tid & 63, g = s >> 2, q = s & 3;
            const float* ep = Esum_s + p * ESTR + g * 68 + q * 16;
            const float* hp = hc_s + p * HH + q * 16;
            const float4v e0 = *(const float4v*)(ep),     h0 = *(const float4v*)(hp);
            const float4v e1 = *(const float4v*)(ep + 4), h1 = *(const float4v*)(hp + 4);
            const float4v e2 = *(const float4v*)(ep + 8), h2 = *(const float4v*)(hp + 8);
            const float4v e3 = *(const float4v*)(ep + 12), h3 = *(const float4v*)(hp + 12);
            float pp = e0[0] * h0[0];
            pp = fmaf(e0[1], h0[1], pp); pp = fmaf(e0[2], h0[2], pp); pp = fmaf(e0[3], h0[3], pp);
            pp = fmaf(e1[0], h1[0], pp); pp = fmaf(e1[1], h1[1], pp);
            pp = fmaf(e1[2], h1[2], pp); pp = fmaf(e1[3], h1[3], pp);
            pp = fmaf(e2[0], h2[0], pp); pp = fmaf(e2[1], h2[1], pp);
            pp = fmaf(e2[2], h2[2], pp); pp = fmaf(e2[3], h2[3], pp);
            pp = fmaf(e3[0], h3[0], pp); pp = fmaf(e3[1], h3[1], pp);
            pp = fmaf(e3[2], h3[2], pp); pp = fmaf(e3[3], h3[3], pp);
            pp += __shfl_xor(pp, 1);
            pp += __shfl_xor(pp, 2);
            if (q == 0) M_s[p * HG + g] = pp;
        }
        __syncthreads();
        if (tid < 192) {   // gate column c=tid for ALL 3 nodes: weights in regs
            float gi0 = bihc, gi1 = bihc, gi2 = bihc;
            #pragma unroll
            for (int jj = 0; jj < 4; ++jj) {
                const float4 w = w_r[jj];
                const float4v m0 = *(const float4v*)(M_s + 0 * HG + 4 * jj);
                const float4v m1 = *(const float4v*)(M_s + 1 * HG + 4 * jj);
                const float4v m2 = *(const float4v*)(M_s + 2 * HG + 4 * jj);
                gi0 = fmaf(m0[0], w.x, gi0); gi0 = fmaf(m0[1], w.y, gi0);
                gi0 = fmaf(m0[2], w.z, gi0); gi0 = fmaf(m0[3], w.w, gi0);
                gi1 = fmaf(m1[0], w.x, gi1); gi1 = fmaf(m1[1], w.y, gi1);
                gi1 = fmaf(m1[2], w.z, gi1); gi1 = fmaf(m1[3], w.w, gi1);
                gi2 = fmaf(m2[0], w.x, gi2); gi2 = fmaf(m2[1], w.y, gi2);
                gi2 = fmaf(m2[2], w.z, gi2); gi2 = fmaf(m2[3], w.w, gi2);
            }
            float gh0 = bhhc, gh1 = bhhc, gh2 = bhhc;
            #pragma unroll
            for (int jj = 4; jj < 20; ++jj) {
                const float4 w = w_r[jj];
                const float4v h0 = *(const float4v*)(hc_s + 0 * HH + 4 * (jj - 4));
                const float4v h1 = *(const float4v*)(hc_s + 1 * HH + 4 * (jj - 4));
                const float4v h2 = *(const float4v*)(hc_s + 2 * HH + 4 * (jj - 4));
                gh0 = fmaf(h0[0], w.x, gh0); gh0 = fmaf(h0[1], w.y, gh0);
                gh0 = fmaf(h0[2], w.z, gh0); gh0 = fmaf(h0[3], w.w, gh0);
                gh1 = fmaf(h1[0], w.x, gh1); gh1 = fmaf(h1[1], w.y, gh1);
                gh1 = fmaf(h1[2], w.z, gh1); gh1 = fmaf(h1[3], w.w, gh1);
                gh2 = fmaf(h2[0], w.x, gh2); gh2 = fmaf(h2[1], w.y, gh2);
                gh2 = fmaf(h2[2], w.z, gh2); gh2 = fmaf(h2[3], w.w, gh2);
            }
            if (tid < 2 * HH) {          // r,z need only the sum
                gsum_s[0 * 2 * HH + tid] = gi0 + gh0;
                gsum_s[1 * 2 * HH + tid] = gi1 + gh1;
                gsum_s[2 * 2 * HH + tid] = gi2 + gh2;
            } else {
                const int c = tid - 2 * HH;
                gin_s[0 * HH + c] = gi0; ghn_s[0 * HH + c] = gh0;
                gin_s[1 * HH + c] = gi1; ghn_s[1 * HH + c] = gh1;
                gin_s[2 * HH + c] = gi2; ghn_s[2 * HH + c] = gh2;
            }
        }
        __syncthreads();
        if (tid < 192) {   // update: thread (p,c) — wave p only; next M phase
            const int p = tid >> 6, c = tid & 63;   // for node p is also wave p,
            const float r = 1.0f / (1.0f + __expf(-gsum_s[p * 2 * HH + c]));      // so no
            const float z = 1.0f / (1.0f + __expf(-gsum_s[p * 2 * HH + HH + c])); // barrier
            const float nin = gin_s[p * HH + c] + r * ghn_s[p * HH + c];          // needed
            const float n = 1.0f - 2.0f / (__expf(2.0f * nin) + 1.0f);  // tanh
            hc_s[p * HH + c] = (1.0f - z) * n + z * hc_s[p * HH + c];
        }
        // no __syncthreads(): update->M (and update->out) is wave/thread-local
    }

    if (tid < 192) out[(size_t)node0 * HH + tid] = hc_s[tid];   // same-thread read
}

extern "C" void kernel_launch(void* const* d_in, const int* in_sizes, int n_in,
                              void* d_out, int out_size, void* d_ws, size_t ws_size,
                              hipStream_t stream) {
    const float* A    = (const float*)d_in[0];
    const float* h    = (const float*)d_in[1];
    const float* E    = (const float*)d_in[2];
    const float* W_h  = (const float*)d_in[3];
    const float* b_h  = (const float*)d_in[4];
    const float* W_e  = (const float*)d_in[5];
    const float* b_e  = (const float*)d_in[6];
    const float* W_ih = (const float*)d_in[7];
    const float* b_ih = (const float*)d_in[8];
    const float* W_hh = (const float*)d_in[9];
    const float* b_hh = (const float*)d_in[10];
    float* out = (float*)d_out;
    (void)d_ws; (void)ws_size;   // workspace no longer used

    hipLaunchKernelGGL(fused_kernel, dim3(NB * NA / P3), dim3(256), 0, stream,
                       A, h, E, W_h, b_h, W_e, b_e, W_ih, b_ih, W_hh, b_hh, out);
}